// Round 9
// baseline (263.125 us; speedup 1.0000x reference)
//
#include <hip/hip_runtime.h>
#include <hip/hip_bf16.h>

typedef __bf16 bf16;
typedef __bf16 bf16x2 __attribute__((ext_vector_type(2)));
typedef __bf16 bf16x8 __attribute__((ext_vector_type(8)));
typedef float f32x4 __attribute__((ext_vector_type(4)));

#define MFMA16(a, b, c) __builtin_amdgcn_mfma_f32_16x16x32_bf16(a, b, c, 0, 0, 0)

// 0.125 (1/sqrt(DK)) * log2(e): folded into Q projection so attention uses exp2.
#define QSCALE 0.18033688f

// ---------------------------------------------------------------------------
// Transpose + f32->bf16 convert the four weight matrices [1024,1024].
// Wt[n][k] = W[k][n].  grid (16,16,4), block 256.
// ---------------------------------------------------------------------------
__global__ __launch_bounds__(256) void transpose_w(const float* __restrict__ w0,
                                                   const float* __restrict__ w1,
                                                   const float* __restrict__ w2,
                                                   const float* __restrict__ w3,
                                                   bf16* __restrict__ dst) {
  __shared__ bf16 T[64][68];
  const float* W = blockIdx.z == 0 ? w0 : blockIdx.z == 1 ? w1
                   : blockIdx.z == 2 ? w2 : w3;
  bf16* Y = dst + (size_t)blockIdx.z * 1024 * 1024;
  const int t = threadIdx.x, r = t >> 2, c4 = t & 3;
  const int k0 = blockIdx.y * 64, n0 = blockIdx.x * 64;

  const float4* src = (const float4*)(W + (size_t)(k0 + r) * 1024 + n0 + c4 * 16);
  float4 f0 = src[0], f1 = src[1], f2 = src[2], f3 = src[3];
  bf16* row = &T[r][c4 * 16];
  row[0] = (bf16)f0.x; row[1] = (bf16)f0.y; row[2] = (bf16)f0.z; row[3] = (bf16)f0.w;
  row[4] = (bf16)f1.x; row[5] = (bf16)f1.y; row[6] = (bf16)f1.z; row[7] = (bf16)f1.w;
  row[8] = (bf16)f2.x; row[9] = (bf16)f2.y; row[10] = (bf16)f2.z; row[11] = (bf16)f2.w;
  row[12] = (bf16)f3.x; row[13] = (bf16)f3.y; row[14] = (bf16)f3.z; row[15] = (bf16)f3.w;
  __syncthreads();

  bf16x8 o0, o1;
#pragma unroll
  for (int j = 0; j < 8; ++j) o0[j] = T[c4 * 16 + j][r];
#pragma unroll
  for (int j = 0; j < 8; ++j) o1[j] = T[c4 * 16 + 8 + j][r];
  bf16* d = Y + (size_t)(n0 + r) * 1024 + k0 + c4 * 16;
  *(bf16x8*)d = o0;
  *(bf16x8*)(d + 8) = o1;
}

// ---------------------------------------------------------------------------
// Pipelined GEMM: (MT*32)x128 tile, BK=64, register-prefetch staging.
// Grid: (M-tiles, 8 N-tiles[, z]) — blocks sharing A-rows have equal flat%8
// -> same XCD -> A re-reads served by that XCD's L2.
// QKV=1 (MT=4): A is f32 (q/k/v), converted to bf16 inline during staging.
//   z=0: -> Qp [B,H,S,DK] scaled; z=1: -> Kp; z=2: -> Vtp [B,H,DK,S] via
//   in-LDS transpose.
// QKV=0 (MT=2): A bf16 (Xp) -> Yf row-major f32.
// ---------------------------------------------------------------------------
template <int QKV, int MT>
__global__ __launch_bounds__(256, 3) void gemm_p(
    const void* __restrict__ x0, const void* __restrict__ x1,
    const void* __restrict__ x2, const bf16* __restrict__ Wt,
    const float* __restrict__ b0, const float* __restrict__ b1,
    const float* __restrict__ b2, bf16* __restrict__ Qp,
    bf16* __restrict__ Kp, bf16* __restrict__ Vtp, float* __restrict__ Yf) {
  constexpr int AROWS = MT * 32;
  __shared__ bf16 Al[AROWS * 72];
  __shared__ bf16 Bl[128 * 72];

  const int z = QKV ? blockIdx.z : 0;
  const bf16* Bt = Wt + (size_t)z * 1048576;
  const float* bias = QKV ? (z == 0 ? b0 : z == 1 ? b1 : b2) : b0;
  const float escale = (QKV && z == 0) ? QSCALE : 1.0f;

  const int t = threadIdx.x;
  const int wave = t >> 6, lane = t & 63, quad = lane >> 4, l16 = lane & 15;
  const int wm = (wave >> 1) * (MT * 16), wn = (wave & 1) * 64;
  const int bm = blockIdx.x * AROWS, bn = blockIdx.y * 128;

  // B staging: 128 rows x 64 k, 32 elems/thread
  const int brow = t >> 1, bcol = (t & 1) * 32;
  const bf16* gB = Bt + (size_t)(bn + brow) * 1024 + bcol;
  bf16x8 rb[4];
#pragma unroll
  for (int j = 0; j < 4; ++j) rb[j] = *(const bf16x8*)(gB + j * 8);

  // A staging
  const int arow = (MT == 4) ? (t >> 1) : (t >> 2);
  const int acol = (MT == 4) ? ((t & 1) * 32) : ((t & 3) * 16);
  const float* gAf = nullptr;
  const bf16* gAb = nullptr;
  float4 raf[8];   // QKV: 32 f32/thread
  bf16x8 rab[2];   // O: 16 bf16/thread
  if (QKV) {
    const float* Xf = z == 0 ? (const float*)x0
                      : z == 1 ? (const float*)x1 : (const float*)x2;
    gAf = Xf + (size_t)(bm + arow) * 1024 + acol;
#pragma unroll
    for (int j = 0; j < 8; ++j) raf[j] = ((const float4*)gAf)[j];
  } else {
    gAb = (const bf16*)x0 + (size_t)(bm + arow) * 1024 + acol;
#pragma unroll
    for (int j = 0; j < 2; ++j) rab[j] = *(const bf16x8*)(gAb + j * 8);
  }

  f32x4 acc[MT][4] = {};

  for (int kb = 0; kb < 1024; kb += 64) {
    __syncthreads();  // all waves done reading previous tile
    if (QKV) {
#pragma unroll
      for (int j = 0; j < 4; ++j) {
        float4 a = raf[2 * j], b = raf[2 * j + 1];
        bf16x8 w;
        w[0] = (bf16)a.x; w[1] = (bf16)a.y; w[2] = (bf16)a.z; w[3] = (bf16)a.w;
        w[4] = (bf16)b.x; w[5] = (bf16)b.y; w[6] = (bf16)b.z; w[7] = (bf16)b.w;
        *(bf16x8*)(Al + arow * 72 + acol + j * 8) = w;
      }
    } else {
#pragma unroll
      for (int j = 0; j < 2; ++j)
        *(bf16x8*)(Al + arow * 72 + acol + j * 8) = rab[j];
    }
#pragma unroll
    for (int j = 0; j < 4; ++j)
      *(bf16x8*)(Bl + brow * 72 + bcol + j * 8) = rb[j];
    __syncthreads();

    if (kb + 64 < 1024) {  // prefetch next tile; lands during compute below
      if (QKV) {
#pragma unroll
        for (int j = 0; j < 8; ++j)
          raf[j] = ((const float4*)(gAf + kb + 64))[j];
      } else {
#pragma unroll
        for (int j = 0; j < 2; ++j)
          rab[j] = *(const bf16x8*)(gAb + kb + 64 + j * 8);
      }
#pragma unroll
      for (int j = 0; j < 4; ++j)
        rb[j] = *(const bf16x8*)(gB + kb + 64 + j * 8);
    }

#pragma unroll
    for (int kk = 0; kk < 2; ++kk) {
      bf16x8 af[MT], bfr[4];
#pragma unroll
      for (int mt = 0; mt < MT; ++mt)
        af[mt] =
            *(const bf16x8*)(Al + (wm + mt * 16 + l16) * 72 + kk * 32 + quad * 8);
#pragma unroll
      for (int nt = 0; nt < 4; ++nt)
        bfr[nt] =
            *(const bf16x8*)(Bl + (wn + nt * 16 + l16) * 72 + kk * 32 + quad * 8);
#pragma unroll
      for (int mt = 0; mt < MT; ++mt)
#pragma unroll
        for (int nt = 0; nt < 4; ++nt)
          acc[mt][nt] = MFMA16(af[mt], bfr[nt], acc[mt][nt]);
    }
  }

  if (QKV && z == 2) {
    // ---- V^T epilogue: in-LDS transpose (Tt aliases Al), coalesced stores
    bf16* Tt = Al;  // 64*136 = 8704 elems <= 128*72 = 9216
    const int b = bm >> 11;
    __syncthreads();
#pragma unroll
    for (int half = 0; half < 2; ++half) {
      if ((wave & 1) == half) {
#pragma unroll
        for (int nt = 0; nt < 4; ++nt) {
          const int ln = nt * 16 + l16;
          const float bia = bias[bn + half * 64 + ln];
#pragma unroll
          for (int mt = 0; mt < 4; ++mt)
#pragma unroll
            for (int r = 0; r < 4; ++r) {
              const int m = wm + mt * 16 + quad * 4 + r;
              Tt[ln * 136 + m] = (bf16)(acc[mt][nt][r] + bia);
            }
        }
      }
      __syncthreads();
      {
        const int ln = t >> 2, seg = (t & 3) * 32;
        const int gn = bn + half * 64 + ln;
        const int h = gn >> 6, dk = gn & 63;
        const int s0 = (bm & 2047) + seg;
        bf16* dstp = Vtp + ((size_t)(b * 16 + h) * 64 + dk) * 2048 + s0;
        const bf16* srcp = Tt + ln * 136 + seg;
#pragma unroll
        for (int j = 0; j < 4; ++j)
          *(bf16x8*)(dstp + j * 8) = *(const bf16x8*)(srcp + j * 8);
      }
      __syncthreads();
    }
  } else {
    // ---- regular epilogue. C/D layout: row = quad*4 + r, col = l16 ----
#pragma unroll
    for (int mt = 0; mt < MT; ++mt)
#pragma unroll
      for (int nt = 0; nt < 4; ++nt) {
        const int gn = bn + wn + nt * 16 + l16;
        const float bia = bias[gn];
#pragma unroll
        for (int r = 0; r < 4; ++r) {
          const int gm = bm + wm + mt * 16 + quad * 4 + r;
          const float val = (acc[mt][nt][r] + bia) * escale;
          if (!QKV) {
            Yf[(size_t)gm * 1024 + gn] = val;
          } else {
            const int b = gm >> 11, s = gm & 2047;  // S = 2048
            const int h = gn >> 6, dk = gn & 63;    // DK = 64
            bf16* Y = (z == 0) ? Qp : Kp;
            Y[((size_t)(b * 16 + h) * 2048 + s) * 64 + dk] = (bf16)val;
          }
        }
      }
  }
}

// ---------------------------------------------------------------------------
// Flash attention, causal, no-running-max, row sums via ones-column MFMA.
// MERGED PAIR: block handles q-tiles {y, 31-y} in ONE key loop — K/V frag
// LDS reads shared between both q-tiles (20 b128 reads serve 36 MFMA/iter).
// Staging iters = (31-y)+1; MFMA work = 33 iter-equivalents (balanced).
// Grid (32 bh, 16 pair): blocks of one bh share flat%8 -> same XCD L2.
// K LDS rows permuted (key kk -> row (kk&32)+(kk&1)*16+((kk&31)>>1)) so P
// columns are key-identity -> packed bf16x2 P writes. Interior tiles skip
// the causal mask (block-uniform).
// ---------------------------------------------------------------------------
__global__ __launch_bounds__(256) void attn_k(const bf16* __restrict__ Q,
                                              const bf16* __restrict__ K,
                                              const bf16* __restrict__ Vt,
                                              bf16* __restrict__ X) {
  __shared__ bf16 Kl[64 * 72];       // K rows permuted
  __shared__ bf16 Vl[64 * 72];       // Vt[d][key]
  __shared__ bf16 PbL[4][16 * 72];   // per-wave P tiles
  __shared__ bf16 PbH[4][16 * 72];

  const int t = threadIdx.x;
  const int wave = t >> 6, lane = t & 63, quad = lane >> 4, l16 = lane & 15;
  const int bh = blockIdx.x, pairx = blockIdx.y;
  const int b = bh >> 4, h = bh & 15;

  const bf16* Qb = Q + (size_t)bh * 2048 * 64;
  const bf16* Kb = K + (size_t)bh * 2048 * 64;
  const bf16* Vb = Vt + (size_t)bh * 64 * 2048;

  const int srow = t >> 2;          // 0..63 (key for K, d for V)
  const int scol = (t & 3) * 16;    // elem col {0,16,32,48}
  const int crow = (srow & 32) + ((srow & 1) << 4) + ((srow & 31) >> 1);

  bf16x8 onesf;
#pragma unroll
  for (int i = 0; i < 8; ++i) onesf[i] = (bf16)1.0f;

  bf16* PwL = PbL[wave];
  bf16* PwH = PbH[wave];

  const int qtL = pairx, qtH = 31 - pairx;
  const int ntiles = qtH + 1;
  const int q0L = qtL * 64 + wave * 16, q0H = qtH * 64 + wave * 16;

  bf16x8 qfL0 = *(const bf16x8*)(Qb + (q0L + l16) * 64 + quad * 8);
  bf16x8 qfL1 = *(const bf16x8*)(Qb + (q0L + l16) * 64 + 32 + quad * 8);
  bf16x8 qfH0 = *(const bf16x8*)(Qb + (q0H + l16) * 64 + quad * 8);
  bf16x8 qfH1 = *(const bf16x8*)(Qb + (q0H + l16) * 64 + 32 + quad * 8);

  f32x4 oL[4] = {}, oH[4] = {};
  f32x4 o4L = {}, o4H = {};

  // prologue: stage tile 0
  {
    const bf16* kp = Kb + srow * 64 + scol;
    const bf16* vp = Vb + (size_t)srow * 2048 + scol;
    bf16x8 k0r = *(const bf16x8*)kp;
    bf16x8 k1r = *(const bf16x8*)(kp + 8);
    bf16x8 v0r = *(const bf16x8*)vp;
    bf16x8 v1r = *(const bf16x8*)(vp + 8);
    *(bf16x8*)(Kl + crow * 72 + scol) = k0r;
    *(bf16x8*)(Kl + crow * 72 + scol + 8) = k1r;
    *(bf16x8*)(Vl + srow * 72 + scol) = v0r;
    *(bf16x8*)(Vl + srow * 72 + scol + 8) = v1r;
  }
  __syncthreads();

  for (int kt = 0; kt < ntiles; ++kt) {
    const int k0 = kt * 64;
    const bool more = (kt + 1) < ntiles;
    const bool loAct = (kt <= qtL);  // block-uniform
    bf16x8 kr0, kr1, vr0, vr1;
    if (more) {  // prefetch next tile
      const bf16* kp = Kb + (k0 + 64 + srow) * 64 + scol;
      const bf16* vp = Vb + (size_t)srow * 2048 + k0 + 64 + scol;
      kr0 = *(const bf16x8*)kp;
      kr1 = *(const bf16x8*)(kp + 8);
      vr0 = *(const bf16x8*)vp;
      vr1 = *(const bf16x8*)(vp + 8);
    }

    // ---- QK^T: K frags shared by both q-tiles ----
    f32x4 scH[4], scL[4];
#pragma unroll
    for (int nt = 0; nt < 4; ++nt) {
      bf16x8 kf0 = *(const bf16x8*)(Kl + (nt * 16 + l16) * 72 + quad * 8);
      bf16x8 kf1 = *(const bf16x8*)(Kl + (nt * 16 + l16) * 72 + 32 + quad * 8);
      f32x4 s = {};
      s = MFMA16(qfH0, kf0, s);
      s = MFMA16(qfH1, kf1, s);
      scH[nt] = s;
      if (loAct) {
        f32x4 s2 = {};
        s2 = MFMA16(qfL0, kf0, s2);
        s2 = MFMA16(qfL1, kf1, s2);
        scL[nt] = s2;
      }
    }

    // ---- softmax + packed P stores (cols key-identity) ----
    {
      const bool interiorH = (k0 + 63) <= q0H;
#pragma unroll
      for (int r = 0; r < 4; ++r) {
        const int row = quad * 4 + r;
        float e0 = exp2f(scH[0][r]), e1 = exp2f(scH[1][r]);
        float e2 = exp2f(scH[2][r]), e3 = exp2f(scH[3][r]);
        if (!interiorH) {
          const int qg = q0H + row, key0 = k0 + 2 * l16;
          if (key0 > qg) e0 = 0.f;
          if (key0 + 1 > qg) e1 = 0.f;
          if (key0 + 32 > qg) e2 = 0.f;
          if (key0 + 33 > qg) e3 = 0.f;
        }
        bf16x2 p01, p23;
        p01[0] = (bf16)e0; p01[1] = (bf16)e1;
        p23[0] = (bf16)e2; p23[1] = (bf16)e3;
        *(bf16x2*)(PwH + row * 72 + 2 * l16) = p01;
        *(bf16x2*)(PwH + row * 72 + 32 + 2 * l16) = p23;
      }
    }
    if (loAct) {
      const bool interiorL = (k0 + 63) <= q0L;
#pragma unroll
      for (int r = 0; r < 4; ++r) {
        const int row = quad * 4 + r;
        float e0 = exp2f(scL[0][r]), e1 = exp2f(scL[1][r]);
        float e2 = exp2f(scL[2][r]), e3 = exp2f(scL[3][r]);
        if (!interiorL) {
          const int qg = q0L + row, key0 = k0 + 2 * l16;
          if (key0 > qg) e0 = 0.f;
          if (key0 + 1 > qg) e1 = 0.f;
          if (key0 + 32 > qg) e2 = 0.f;
          if (key0 + 33 > qg) e3 = 0.f;
        }
        bf16x2 p01, p23;
        p01[0] = (bf16)e0; p01[1] = (bf16)e1;
        p23[0] = (bf16)e2; p23[1] = (bf16)e3;
        *(bf16x2*)(PwL + row * 72 + 2 * l16) = p01;
        *(bf16x2*)(PwL + row * 72 + 32 + 2 * l16) = p23;
      }
    }
    __builtin_amdgcn_s_waitcnt(0xC07F);  // lgkmcnt(0): P visible to wave

    // ---- PV + row sums; V frags shared by both q-tiles ----
    bf16x8 pH0 = *(const bf16x8*)(PwH + l16 * 72 + quad * 8);
    bf16x8 pH1 = *(const bf16x8*)(PwH + l16 * 72 + 32 + quad * 8);
    o4H = MFMA16(pH0, onesf, o4H);
    o4H = MFMA16(pH1, onesf, o4H);
    bf16x8 pL0, pL1;
    if (loAct) {
      pL0 = *(const bf16x8*)(PwL + l16 * 72 + quad * 8);
      pL1 = *(const bf16x8*)(PwL + l16 * 72 + 32 + quad * 8);
      o4L = MFMA16(pL0, onesf, o4L);
      o4L = MFMA16(pL1, onesf, o4L);
    }
#pragma unroll
    for (int dt = 0; dt < 4; ++dt) {
      bf16x8 vf0 = *(const bf16x8*)(Vl + (dt * 16 + l16) * 72 + quad * 8);
      bf16x8 vf1 = *(const bf16x8*)(Vl + (dt * 16 + l16) * 72 + 32 + quad * 8);
      oH[dt] = MFMA16(pH0, vf0, oH[dt]);
      oH[dt] = MFMA16(pH1, vf1, oH[dt]);
      if (loAct) {
        oL[dt] = MFMA16(pL0, vf0, oL[dt]);
        oL[dt] = MFMA16(pL1, vf1, oL[dt]);
      }
    }

    __syncthreads();  // all waves done reading Kl/Vl
    if (more) {
      *(bf16x8*)(Kl + crow * 72 + scol) = kr0;
      *(bf16x8*)(Kl + crow * 72 + scol + 8) = kr1;
      *(bf16x8*)(Vl + srow * 72 + scol) = vr0;
      *(bf16x8*)(Vl + srow * 72 + scol + 8) = vr1;
      __syncthreads();
    }
  }

  // epilogue: normalize + store both q-tiles to [B,S,1024]
#pragma unroll
  for (int r = 0; r < 4; ++r) {
    const float rinvL = 1.0f / o4L[r];
    const float rinvH = 1.0f / o4H[r];
    const int qgL = q0L + quad * 4 + r;
    const int qgH = q0H + quad * 4 + r;
#pragma unroll
    for (int dt = 0; dt < 4; ++dt) {
      const int col = h * 64 + dt * 16 + l16;
      X[((size_t)b * 2048 + qgL) * 1024 + col] = (bf16)(oL[dt][r] * rinvL);
      X[((size_t)b * 2048 + qgH) * 1024 + col] = (bf16)(oH[dt][r] * rinvH);
    }
  }
}

// ---------------------------------------------------------------------------
extern "C" void kernel_launch(void* const* d_in, const int* in_sizes, int n_in,
                              void* d_out, int out_size, void* d_ws,
                              size_t ws_size, hipStream_t stream) {
  const float* q = (const float*)d_in[0];
  const float* k = (const float*)d_in[1];
  const float* v = (const float*)d_in[2];
  const float* w_q = (const float*)d_in[4];
  const float* b_q = (const float*)d_in[5];
  const float* w_k = (const float*)d_in[6];
  const float* b_k = (const float*)d_in[7];
  const float* w_v = (const float*)d_in[8];
  const float* b_v = (const float*)d_in[9];
  const float* w_o = (const float*)d_in[10];
  const float* b_o = (const float*)d_in[11];

  bf16* ws = (bf16*)d_ws;
  const size_t NELEM = (size_t)4096 * 1024;
  bf16* Qp = ws;                // [B,H,S,DK]
  bf16* Kp = ws + NELEM;        // [B,H,S,DK]
  bf16* Vtp = ws + 2 * NELEM;   // [B,H,DK,S]
  bf16* Xp = ws + 3 * NELEM;    // [B,S,D] attn out
  bf16* Wt = ws + 4 * NELEM;    // 4 x [1024,1024] transposed bf16 weights
  bf16* Wto = Wt + 3145728;

  transpose_w<<<dim3(16, 16, 4), 256, 0, stream>>>(w_q, w_k, w_v, w_o, Wt);

  // fused Q/K/V projections (f32 A, inline cvt): grid (32 m, 8 n, 3 z)
  gemm_p<1, 4><<<dim3(32, 8, 3), 256, 0, stream>>>(
      q, k, v, Wt, b_q, b_k, b_v, Qp, Kp, Vtp, nullptr);
  attn_k<<<dim3(32, 16), 256, 0, stream>>>(Qp, Kp, Vtp, Xp);
  // O projection: grid (64 m, 8 n)
  gemm_p<0, 2><<<dim3(64, 8), 256, 0, stream>>>(
      Xp, nullptr, nullptr, Wto, b_o, nullptr, nullptr, nullptr, nullptr,
      nullptr, (float*)d_out);
}